// Round 1
// 863.730 us; speedup vs baseline: 1.0962x; 1.0962x over previous
//
#include <hip/hip_runtime.h>
#include <hip/hip_bf16.h>
#include <math.h>
#include <stdint.h>

#define DIM   256
#define NSEQ  65536
#define NTOK  131072
#define HEADS 8
#define HD    32
#define WSZ   64
#define NWIN  2048
#define QKVN  768
#define MLPD  1024
#define LNEPS 1e-5f

typedef __bf16 bf16;
typedef __bf16 bf16x8 __attribute__((ext_vector_type(8)));
typedef __bf16 bf16x4 __attribute__((ext_vector_type(4)));
typedef float  f32x4  __attribute__((ext_vector_type(4)));

// rolled-window row rp -> source/original token index (shift = 32, per batch of 65536)
__device__ __forceinline__ int roll_row(int r) {
  return (r & 0x10000) | ((r + 32) & 0xFFFF);
}

// fast GELU: tanh-approx rewritten as v * sigmoid(1.5957691*v + 0.0713548*v^3).
// |err| vs exact-erf gelu < ~1e-3, below bf16 quantization of the g buffer.
__device__ __forceinline__ float fast_gelu(float v) {
  const float x2 = v * v;
  const float z2 = v * __builtin_fmaf(x2, 0.07135481630268f, 1.5957691216057308f);
  const float e  = __expf(z2);
  const float r  = __builtin_amdgcn_rcpf(e + 1.0f);
  return __builtin_fmaf(-v, r, v);   // v * (1 - r) = v * sigmoid(z2)
}

// XCD-chunked bijective block swizzle, N-block fastest within each XCD chunk.
// Requires gridDim.x % 8 == 0 and (gridDim.x/8) % NY == 0 (true for all launches).
template<int NY>
__device__ __forceinline__ void grid_swz(int& mBase, int& nBase) {
  const int nwg  = gridDim.x;
  const int lin  = blockIdx.x;
  const int orig = (lin & 7) * (nwg >> 3) + (lin >> 3);
  mBase = (orig / NY) * 128;
  nBase = (orig % NY) * 128;
}

// ---- async global->LDS 16B stage. LDS dest is wave-uniform base + lane*16.
__device__ __forceinline__ void stage16(const bf16* g, bf16* l) {
#if __has_builtin(__builtin_amdgcn_global_load_lds)
  __builtin_amdgcn_global_load_lds((const __attribute__((address_space(1))) void*)g,
                                   (__attribute__((address_space(3))) void*)l, 16, 0, 0);
#else
  int lane = threadIdx.x & 63;
  *(uint4*)((char*)l + lane * 16) = *(const uint4*)g;
#endif
}

// ============================================================================
// GEMM core: C[128x128] = A[128xK] * Bt[128xK]^T  (A row-major, Bt = B^T row-major)
// 256 threads = 4 waves in 2x2, wave tile 64x64 via 16 x mfma_f32_16x16x32_bf16.
// LDS tiles [128][32] bf16, XOR-swizzled 16B chunks so frag reads are conflict-free.
// ============================================================================
template<int K, int LDB, bool ROLL>
__device__ __forceinline__ void gemm_tile(const bf16* __restrict__ A,
                                          const bf16* __restrict__ Bt,
                                          int mBase, int nBase,
                                          bf16* sA, bf16* sB,
                                          f32x4 acc[4][4])
{
  const int tid  = threadIdx.x;
  const int wave = tid >> 6;
  const int lane = tid & 63;
  const int slot = lane & 3;
  const int swz  = (lane >> 3) & 3;          // ((tile_row>>1)&3) for this lane's staging row
  const int rloc = lane >> 2;                // 0..15
  const int chunk = ((slot ^ swz) * 8);      // swizzled k-chunk (elements)

  int lr0 = mBase + wave * 32 + rloc;
  int lr1 = lr0 + 16;
  int ar0 = ROLL ? roll_row(lr0) : lr0;
  int ar1 = ROLL ? roll_row(lr1) : lr1;
  const bf16* gA0 = A + (size_t)ar0 * K + chunk;
  const bf16* gA1 = A + (size_t)ar1 * K + chunk;
  const bf16* gB0 = Bt + (size_t)(nBase + wave * 32 + rloc) * LDB + chunk;
  const bf16* gB1 = Bt + (size_t)(nBase + wave * 32 + rloc + 16) * LDB + chunk;

  bf16* dA0 = sA + (wave * 32 +  0) * 32;
  bf16* dA1 = sA + (wave * 32 + 16) * 32;
  bf16* dB0 = sB + (wave * 32 +  0) * 32;
  bf16* dB1 = sB + (wave * 32 + 16) * 32;

  const int m0 = (wave & 1) * 64;
  const int n0 = (wave >> 1) * 64;
  const int c    = lane & 15;
  const int quad = lane >> 4;

  int fa[4], fb[4];
#pragma unroll
  for (int t = 0; t < 4; ++t) {
    int rowA = m0 + t * 16 + c;
    fa[t] = rowA * 32 + ((quad ^ ((rowA >> 1) & 3)) * 8);
    int rowB = n0 + t * 16 + c;
    fb[t] = rowB * 32 + ((quad ^ ((rowB >> 1) & 3)) * 8);
  }

  const f32x4 fzero = {0.f, 0.f, 0.f, 0.f};
#pragma unroll
  for (int i = 0; i < 4; ++i)
#pragma unroll
    for (int j = 0; j < 4; ++j) acc[i][j] = fzero;

  for (int k0 = 0; k0 < K; k0 += 32) {
    stage16(gA0 + k0, dA0);
    stage16(gA1 + k0, dA1);
    stage16(gB0 + k0, dB0);
    stage16(gB1 + k0, dB1);
    __syncthreads();
    bf16x8 afr[4], bfr[4];
#pragma unroll
    for (int t = 0; t < 4; ++t) {
      afr[t] = *(const bf16x8*)(sA + fa[t]);
      bfr[t] = *(const bf16x8*)(sB + fb[t]);
    }
#pragma unroll
    for (int i = 0; i < 4; ++i)
#pragma unroll
      for (int j = 0; j < 4; ++j)
        acc[i][j] = __builtin_amdgcn_mfma_f32_16x16x32_bf16(afr[i], bfr[j], acc[i][j], 0, 0, 0);
    __syncthreads();
  }
}

// ============================================================================
// prep: weights -> [N][K] bf16 transposes; pos_emb -> MFMA C-layout order
// ============================================================================
__global__ __launch_bounds__(256) void k_prep(const float* __restrict__ wqkv,
                                              const float* __restrict__ wout,
                                              const float* __restrict__ w1,
                                              const float* __restrict__ w2,
                                              const float* __restrict__ pos,
                                              bf16* __restrict__ wqkvT, bf16* __restrict__ woutT,
                                              bf16* __restrict__ w1T, bf16* __restrict__ w2T,
                                              float* __restrict__ posP)
{
  const int total = 768 * 256 + 256 * 256 + 1024 * 256 + 256 * 1024 + 4096;
  for (int i = blockIdx.x * 256 + threadIdx.x; i < total; i += gridDim.x * 256) {
    int j = i;
    if (j < 768 * 256) { int n = j >> 8, k = j & 255; wqkvT[j] = (bf16)wqkv[k * 768 + n]; continue; }
    j -= 768 * 256;
    if (j < 256 * 256) { int n = j >> 8, k = j & 255; woutT[j] = (bf16)wout[k * 256 + n]; continue; }
    j -= 256 * 256;
    if (j < 1024 * 256) { int n = j >> 8, k = j & 255; w1T[j] = (bf16)w1[k * 1024 + n]; continue; }
    j -= 1024 * 256;
    if (j < 256 * 1024) { int n = j >> 10, k = j & 1023; w2T[j] = (bf16)w2[k * 256 + n]; continue; }
    j -= 256 * 1024;
    { // posP[((mt*4+r)*4+nt)*64 + lane] = pos[i][j] at (i=mt*16+quad*4+r, j=nt*16+c)
      int lane = j & 63, t = j >> 6;
      int nt = t & 3, r = (t >> 2) & 3, mt = t >> 4;
      int ii = mt * 16 + (lane >> 4) * 4 + r, jj = nt * 16 + (lane & 15);
      posP[j] = pos[ii * 64 + jj];
    }
  }
}

// ============================================================================
// layernorm: one wave per token (256 dims = 64 lanes x float4), out bf16
// ============================================================================
__global__ __launch_bounds__(256) void k_ln(const float* __restrict__ x,
                                            const float* __restrict__ gam,
                                            const float* __restrict__ bet,
                                            bf16* __restrict__ out)
{
  const int wave = threadIdx.x >> 6, lane = threadIdx.x & 63;
  const int token = blockIdx.x * 4 + wave;
  const float4 v = ((const float4*)x)[(size_t)token * 64 + lane];
  float s = v.x + v.y + v.z + v.w;
  float q = v.x * v.x + v.y * v.y + v.z * v.z + v.w * v.w;
#pragma unroll
  for (int off = 32; off; off >>= 1) { s += __shfl_xor(s, off); q += __shfl_xor(q, off); }
  const float mu = s * (1.f / 256.f);
  const float var = q * (1.f / 256.f) - mu * mu;
  const float rs = rsqrtf(var + LNEPS);
  const float4 gv = ((const float4*)gam)[lane];
  const float4 bv = ((const float4*)bet)[lane];
  bf16x4 o;
  o[0] = (bf16)((v.x - mu) * rs * gv.x + bv.x);
  o[1] = (bf16)((v.y - mu) * rs * gv.y + bv.y);
  o[2] = (bf16)((v.z - mu) * rs * gv.z + bv.z);
  o[3] = (bf16)((v.w - mu) * rs * gv.w + bv.w);
  *(bf16x4*)(out + (size_t)token * 256 + lane * 4) = o;
}

// ============================================================================
// qkv GEMM: rows read with roll; qkv written in rolled (window) order, bf16
// ============================================================================
__global__ __launch_bounds__(256, 2) void k_gemm_qkv(const bf16* __restrict__ h1,
                                                     const bf16* __restrict__ wqkvT,
                                                     bf16* __restrict__ qkv)
{
  __shared__ __align__(16) bf16 sA[128 * 32];
  __shared__ __align__(16) bf16 sB[128 * 32];
  f32x4 acc[4][4];
  int mBase, nBase;
  grid_swz<6>(mBase, nBase);
  gemm_tile<256, 256, true>(h1, wqkvT, mBase, nBase, sA, sB, acc);
  const int lane = threadIdx.x & 63, wave = threadIdx.x >> 6;
  const int c = lane & 15, quad = lane >> 4;
  const int rowBase = mBase + (wave & 1) * 64 + quad * 4;
  const int colBase = nBase + (wave >> 1) * 64 + c;
#pragma unroll
  for (int i = 0; i < 4; ++i)
#pragma unroll
    for (int j = 0; j < 4; ++j)
#pragma unroll
      for (int r = 0; r < 4; ++r)
        qkv[(size_t)(rowBase + i * 16 + r) * QKVN + (colBase + j * 16)] = (bf16)acc[i][j][r];
}

// ============================================================================
// attention: block = 4 waves, one (window, head) per wave; grid (NWIN, 2)
// ============================================================================
__global__ __launch_bounds__(256, 2) void k_attn(const bf16* __restrict__ qkv,
                                                 const float* __restrict__ posP,
                                                 bf16* __restrict__ attn)
{
  __shared__ __align__(16) bf16 sQ[4][64 * 40];  // q [64][32] pad->40 ; reused for P staging
  __shared__ __align__(16) bf16 sK[4][64 * 40];  // k [64][32] pad->40
  __shared__ __align__(16) bf16 sV[4][32 * 72];  // v^T [32][64] pad->72
  const int tid = threadIdx.x;
  const int wave = tid >> 6, lane = tid & 63;
  const int gh = blockIdx.y * 4 + wave;          // global head
  const int win = blockIdx.x;
  const int c = lane & 15, quad = lane >> 4;
  const size_t base = (size_t)win * 64 * QKVN;

  { // q,k: 16B vector loads -> padded LDS
    const int row = lane >> 2;
    const int col = (lane & 3) * 8;
#pragma unroll
    for (int i = 0; i < 4; ++i) {
      int rr = i * 16 + row;
      *(uint4*)(&sQ[wave][rr * 40 + col]) = *(const uint4*)(qkv + base + (size_t)rr * QKVN + gh * 32 + col);
      *(uint4*)(&sK[wave][rr * 40 + col]) = *(const uint4*)(qkv + base + (size_t)rr * QKVN + 256 + gh * 32 + col);
    }
  }
  { // v transposed into [d][j]
    const int d = lane & 31, jh = lane >> 5;
#pragma unroll
    for (int it = 0; it < 32; ++it) {
      int j = it * 2 + jh;
      sV[wave][d * 72 + j] = qkv[base + (size_t)j * QKVN + 512 + gh * 32 + d];
    }
  }

  // ---- S = Q K^T (per-wave private LDS regions; no block barrier needed)
  const f32x4 fzero = {0.f, 0.f, 0.f, 0.f};
  f32x4 sacc[4][4];
#pragma unroll
  for (int i = 0; i < 4; ++i)
#pragma unroll
    for (int j = 0; j < 4; ++j) sacc[i][j] = fzero;
  bf16x8 qf[4], kf[4];
#pragma unroll
  for (int t = 0; t < 4; ++t) {
    qf[t] = *(const bf16x8*)(&sQ[wave][(t * 16 + c) * 40 + quad * 8]);
    kf[t] = *(const bf16x8*)(&sK[wave][(t * 16 + c) * 40 + quad * 8]);
  }
#pragma unroll
  for (int i = 0; i < 4; ++i)
#pragma unroll
    for (int j = 0; j < 4; ++j)
      sacc[i][j] = __builtin_amdgcn_mfma_f32_16x16x32_bf16(qf[i], kf[j], sacc[i][j], 0, 0, 0);

  // ---- scores: scale + pos, row softmax (rows live across 16-lane groups)
  const float scale = 0.17677669529663687f; // 1/sqrt(32)
  float p[4][4][4];
#pragma unroll
  for (int i = 0; i < 4; ++i)
#pragma unroll
    for (int j = 0; j < 4; ++j)
#pragma unroll
      for (int r = 0; r < 4; ++r)
        p[i][j][r] = sacc[i][j][r] * scale + posP[(((i * 4 + r) * 4 + j) << 6) + lane];

  float mx[4][4], rcp[4][4];
#pragma unroll
  for (int i = 0; i < 4; ++i)
#pragma unroll
    for (int r = 0; r < 4; ++r) {
      float m = fmaxf(fmaxf(p[i][0][r], p[i][1][r]), fmaxf(p[i][2][r], p[i][3][r]));
      m = fmaxf(m, __shfl_xor(m, 1)); m = fmaxf(m, __shfl_xor(m, 2));
      m = fmaxf(m, __shfl_xor(m, 4)); m = fmaxf(m, __shfl_xor(m, 8));
      mx[i][r] = m;
    }
#pragma unroll
  for (int i = 0; i < 4; ++i)
#pragma unroll
    for (int r = 0; r < 4; ++r) {
#pragma unroll
      for (int j = 0; j < 4; ++j) p[i][j][r] = __expf(p[i][j][r] - mx[i][r]);
      float t = p[i][0][r] + p[i][1][r] + p[i][2][r] + p[i][3][r];
      t += __shfl_xor(t, 1); t += __shfl_xor(t, 2); t += __shfl_xor(t, 4); t += __shfl_xor(t, 8);
      rcp[i][r] = 1.0f / t;
    }
#pragma unroll
  for (int i = 0; i < 4; ++i)
#pragma unroll
    for (int j = 0; j < 4; ++j)
#pragma unroll
      for (int r = 0; r < 4; ++r) p[i][j][r] *= rcp[i][r];

  // ---- O = P V  (P -> LDS (A-layout) in two j-halves, reusing sQ)
  f32x4 oacc[4][2];
#pragma unroll
  for (int i = 0; i < 4; ++i) { oacc[i][0] = fzero; oacc[i][1] = fzero; }
#pragma unroll
  for (int half = 0; half < 2; ++half) {
#pragma unroll
    for (int i = 0; i < 4; ++i)
#pragma unroll
      for (int j2 = 0; j2 < 2; ++j2)
#pragma unroll
        for (int r = 0; r < 4; ++r)
          sQ[wave][(i * 16 + quad * 4 + r) * 40 + j2 * 16 + c] = (bf16)p[i][half * 2 + j2][r];
    bf16x8 pf[4], vf[2];
#pragma unroll
    for (int t = 0; t < 4; ++t)
      pf[t] = *(const bf16x8*)(&sQ[wave][(t * 16 + c) * 40 + quad * 8]);
#pragma unroll
    for (int n2 = 0; n2 < 2; ++n2)
      vf[n2] = *(const bf16x8*)(&sV[wave][(n2 * 16 + c) * 72 + half * 32 + quad * 8]);
#pragma unroll
    for (int i = 0; i < 4; ++i)
#pragma unroll
      for (int n2 = 0; n2 < 2; ++n2)
        oacc[i][n2] = __builtin_amdgcn_mfma_f32_16x16x32_bf16(pf[i], vf[n2], oacc[i][n2], 0, 0, 0);
  }

#pragma unroll
  for (int i = 0; i < 4; ++i)
#pragma unroll
    for (int n2 = 0; n2 < 2; ++n2)
#pragma unroll
      for (int r = 0; r < 4; ++r)
        attn[(size_t)(win * 64 + i * 16 + quad * 4 + r) * DIM + gh * 32 + n2 * 16 + c] = (bf16)oacc[i][n2][r];
}

// ============================================================================
// out-proj GEMM + b_out + residual(x) with un-roll -> x2 (f32, into d_out)
// ============================================================================
__global__ __launch_bounds__(256, 2) void k_gemm_proj(const bf16* __restrict__ attn,
                                                      const bf16* __restrict__ woutT,
                                                      const float* __restrict__ x,
                                                      const float* __restrict__ b_out,
                                                      float* __restrict__ x2)
{
  __shared__ __align__(16) bf16 sA[128 * 32];
  __shared__ __align__(16) bf16 sB[128 * 32];
  f32x4 acc[4][4];
  int mBase, nBase;
  grid_swz<2>(mBase, nBase);
  gemm_tile<256, 256, false>(attn, woutT, mBase, nBase, sA, sB, acc);
  const int lane = threadIdx.x & 63, wave = threadIdx.x >> 6;
  const int c = lane & 15, quad = lane >> 4;
  const int rowBase = mBase + (wave & 1) * 64 + quad * 4;
  const int colBase = nBase + (wave >> 1) * 64 + c;
#pragma unroll
  for (int i = 0; i < 4; ++i)
#pragma unroll
    for (int r = 0; r < 4; ++r) {
      const int rp = rowBase + i * 16 + r;
      const size_t rowoff = (size_t)roll_row(rp) * DIM;
#pragma unroll
      for (int j = 0; j < 4; ++j) {
        const int col = colBase + j * 16;
        x2[rowoff + col] = acc[i][j][r] + b_out[col] + x[rowoff + col];
      }
    }
}

// ============================================================================
// mlp1: h2 @ w1T(half) + b1 -> fast gelu -> g (bf16, ldc=512)
// ============================================================================
__global__ __launch_bounds__(256, 2) void k_gemm_mlp1(const bf16* __restrict__ h2,
                                                      const bf16* __restrict__ w1Th,
                                                      const float* __restrict__ b1h,
                                                      bf16* __restrict__ g)
{
  __shared__ __align__(16) bf16 sA[128 * 32];
  __shared__ __align__(16) bf16 sB[128 * 32];
  f32x4 acc[4][4];
  int mBase, nBase;
  grid_swz<4>(mBase, nBase);
  gemm_tile<256, 256, false>(h2, w1Th, mBase, nBase, sA, sB, acc);
  const int lane = threadIdx.x & 63, wave = threadIdx.x >> 6;
  const int c = lane & 15, quad = lane >> 4;
  const int rowBase = mBase + (wave & 1) * 64 + quad * 4;
  const int colBase = nBase + (wave >> 1) * 64 + c;
#pragma unroll
  for (int i = 0; i < 4; ++i)
#pragma unroll
    for (int j = 0; j < 4; ++j) {
      const int col = colBase + j * 16;
      const float bb = b1h[col];
#pragma unroll
      for (int r = 0; r < 4; ++r) {
        const float v = acc[i][j][r] + bb;
        g[(size_t)(rowBase + i * 16 + r) * 512 + col] = (bf16)fast_gelu(v);
      }
    }
}

// ============================================================================
// mlp2: g(K=512) @ w2T(half, ldb=1024) [+ b2] accumulated into d_out (x2 resident)
// ============================================================================
__global__ __launch_bounds__(256, 2) void k_gemm_mlp2(const bf16* __restrict__ g,
                                                      const bf16* __restrict__ w2Th,
                                                      const float* __restrict__ b2,
                                                      float* __restrict__ out,
                                                      int first)
{
  __shared__ __align__(16) bf16 sA[128 * 32];
  __shared__ __align__(16) bf16 sB[128 * 32];
  f32x4 acc[4][4];
  int mBase, nBase;
  grid_swz<2>(mBase, nBase);
  gemm_tile<512, 1024, false>(g, w2Th, mBase, nBase, sA, sB, acc);
  const int lane = threadIdx.x & 63, wave = threadIdx.x >> 6;
  const int c = lane & 15, quad = lane >> 4;
  const int rowBase = mBase + (wave & 1) * 64 + quad * 4;
  const int colBase = nBase + (wave >> 1) * 64 + c;
#pragma unroll
  for (int i = 0; i < 4; ++i)
#pragma unroll
    for (int j = 0; j < 4; ++j) {
      const int col = colBase + j * 16;
      const float bb = first ? b2[col] : 0.0f;
#pragma unroll
      for (int r = 0; r < 4; ++r) {
        const size_t off = (size_t)(rowBase + i * 16 + r) * DIM + col;
        out[off] = out[off] + acc[i][j][r] + bb;
      }
    }
}

// ============================================================================
extern "C" void kernel_launch(void* const* d_in, const int* in_sizes, int n_in,
                              void* d_out, int out_size, void* d_ws, size_t ws_size,
                              hipStream_t stream) {
  const float* x    = (const float*)d_in[0];
  const float* wqkv = (const float*)d_in[1];
  const float* wout = (const float*)d_in[2];
  const float* bo   = (const float*)d_in[3];
  const float* pos  = (const float*)d_in[4];
  const float* l1g  = (const float*)d_in[5];
  const float* l1b  = (const float*)d_in[6];
  const float* w1   = (const float*)d_in[7];
  const float* b1   = (const float*)d_in[8];
  const float* w2   = (const float*)d_in[9];
  const float* b2   = (const float*)d_in[10];
  const float* l2g  = (const float*)d_in[11];
  const float* l2b  = (const float*)d_in[12];
  float* out = (float*)d_out;

  char* ws = (char*)d_ws;
  bf16* h1   = (bf16*)ws;                              // 67,108,864 B
  bf16* qkv  = (bf16*)(ws + 67108864);                 // 201,326,592 B
  bf16* attn = h1;                                     // reuse (h1 dead after qkv GEMM)
  bf16* h2   = qkv;                                    // reuse (qkv dead after attn), 67 MB
  bf16* gbuf = (bf16*)(ws + 134217728);                // 134 MB, second part of qkv region
  char* wp = ws + 268435456;
  bf16* wqkvT = (bf16*)wp;  wp += 768 * 256 * 2;
  bf16* woutT = (bf16*)wp;  wp += 256 * 256 * 2;
  bf16* w1T   = (bf16*)wp;  wp += 1024 * 256 * 2;
  bf16* w2T   = (bf16*)wp;  wp += 256 * 1024 * 2;
  float* posP = (float*)wp;                            // 4096 f32

  k_prep<<<dim3(1024), dim3(256), 0, stream>>>(wqkv, wout, w1, w2, pos, wqkvT, woutT, w1T, w2T, posP);
  k_ln<<<dim3(NTOK / 4), dim3(256), 0, stream>>>(x, l1g, l1b, h1);
  k_gemm_qkv<<<dim3(6144), dim3(256), 0, stream>>>(h1, wqkvT, qkv);
  k_attn<<<dim3(NWIN, 2), dim3(256), 0, stream>>>(qkv, posP, attn);
  k_gemm_proj<<<dim3(2048), dim3(256), 0, stream>>>(attn, woutT, x, bo, out);
  k_ln<<<dim3(NTOK / 4), dim3(256), 0, stream>>>(out, l2g, l2b, h2);
  for (int half = 0; half < 2; ++half) {
    k_gemm_mlp1<<<dim3(4096), dim3(256), 0, stream>>>(h2, w1T + half * 512 * 256, b1 + half * 512, gbuf);
    k_gemm_mlp2<<<dim3(2048), dim3(256), 0, stream>>>(gbuf, w2T + half * 512, b2, out, half == 0 ? 1 : 0);
  }
}

// Round 2
// 797.477 us; speedup vs baseline: 1.1873x; 1.0831x over previous
//
#include <hip/hip_runtime.h>
#include <hip/hip_bf16.h>
#include <math.h>
#include <stdint.h>

#define DIM   256
#define NSEQ  65536
#define NTOK  131072
#define HEADS 8
#define HD    32
#define WSZ   64
#define NWIN  2048
#define QKVN  768
#define MLPD  1024
#define LNEPS 1e-5f

typedef __bf16 bf16;
typedef __bf16 bf16x8 __attribute__((ext_vector_type(8)));
typedef __bf16 bf16x4 __attribute__((ext_vector_type(4)));
typedef float  f32x4  __attribute__((ext_vector_type(4)));

// rolled-window row rp -> source/original token index (shift = 32, per batch of 65536)
__device__ __forceinline__ int roll_row(int r) {
  return (r & 0x10000) | ((r + 32) & 0xFFFF);
}

// fast GELU: tanh-approx rewritten as v * sigmoid(1.5957691*v + 0.0713548*v^3).
// |err| vs exact-erf gelu < ~1e-3, below bf16 quantization of the g buffer.
__device__ __forceinline__ float fast_gelu(float v) {
  const float x2 = v * v;
  const float z2 = v * __builtin_fmaf(x2, 0.07135481630268f, 1.5957691216057308f);
  const float e  = __expf(z2);
  const float r  = __builtin_amdgcn_rcpf(e + 1.0f);
  return __builtin_fmaf(-v, r, v);   // v * (1 - r) = v * sigmoid(z2)
}

// XCD-chunked bijective block swizzle, N-block fastest within each XCD chunk.
// Requires gridDim.x % 8 == 0 and (gridDim.x/8) % NY == 0 (true for all launches).
template<int NY>
__device__ __forceinline__ void grid_swz(int& mBase, int& nBase) {
  const int nwg  = gridDim.x;
  const int lin  = blockIdx.x;
  const int orig = (lin & 7) * (nwg >> 3) + (lin >> 3);
  mBase = (orig / NY) * 128;
  nBase = (orig % NY) * 128;
}

// ---- async global->LDS 16B stage. LDS dest is wave-uniform base + lane*16.
__device__ __forceinline__ void stage16(const bf16* g, bf16* l) {
#if __has_builtin(__builtin_amdgcn_global_load_lds)
  __builtin_amdgcn_global_load_lds((const __attribute__((address_space(1))) void*)g,
                                   (__attribute__((address_space(3))) void*)l, 16, 0, 0);
#else
  int lane = threadIdx.x & 63;
  *(uint4*)((char*)l + lane * 16) = *(const uint4*)g;
#endif
}

// ============================================================================
// GEMM core: C[128x128] = A[128xK] * Bt[128xK]^T  (A row-major, Bt = B^T row-major)
// 256 threads = 4 waves in 2x2, wave tile 64x64 via 16 x mfma_f32_16x16x32_bf16.
// Double-buffered LDS tiles [2][128][32] bf16, XOR-swizzled 16B chunks.
// 2-phase pipeline: issue stage(t+1) BEFORE computing tile t; one barrier/iter.
// ============================================================================
template<int K, int LDB, bool ROLL>
__device__ __forceinline__ void gemm_tile(const bf16* __restrict__ A,
                                          const bf16* __restrict__ Bt,
                                          int mBase, int nBase,
                                          bf16* sA, bf16* sB,   // each [2*128*32]
                                          f32x4 acc[4][4])
{
  const int tid  = threadIdx.x;
  const int wave = tid >> 6;
  const int lane = tid & 63;
  const int slot = lane & 3;
  const int swz  = (lane >> 3) & 3;          // ((tile_row>>1)&3) for this lane's staging row
  const int rloc = lane >> 2;                // 0..15
  const int chunk = ((slot ^ swz) * 8);      // swizzled k-chunk (elements)

  int lr0 = mBase + wave * 32 + rloc;
  int lr1 = lr0 + 16;
  int ar0 = ROLL ? roll_row(lr0) : lr0;
  int ar1 = ROLL ? roll_row(lr1) : lr1;
  const bf16* gA0 = A + (size_t)ar0 * K + chunk;
  const bf16* gA1 = A + (size_t)ar1 * K + chunk;
  const bf16* gB0 = Bt + (size_t)(nBase + wave * 32 + rloc) * LDB + chunk;
  const bf16* gB1 = Bt + (size_t)(nBase + wave * 32 + rloc + 16) * LDB + chunk;

  bf16* dA0 = sA + (wave * 32 +  0) * 32;
  bf16* dA1 = sA + (wave * 32 + 16) * 32;
  bf16* dB0 = sB + (wave * 32 +  0) * 32;
  bf16* dB1 = sB + (wave * 32 + 16) * 32;

  const int m0 = (wave & 1) * 64;
  const int n0 = (wave >> 1) * 64;
  const int c    = lane & 15;
  const int quad = lane >> 4;

  int fa[4], fb[4];
#pragma unroll
  for (int t = 0; t < 4; ++t) {
    int rowA = m0 + t * 16 + c;
    fa[t] = rowA * 32 + ((quad ^ ((rowA >> 1) & 3)) * 8);
    int rowB = n0 + t * 16 + c;
    fb[t] = rowB * 32 + ((quad ^ ((rowB >> 1) & 3)) * 8);
  }

  const f32x4 fzero = {0.f, 0.f, 0.f, 0.f};
#pragma unroll
  for (int i = 0; i < 4; ++i)
#pragma unroll
    for (int j = 0; j < 4; ++j) acc[i][j] = fzero;

  // prologue: stage tile 0 into buffer 0
  stage16(gA0, dA0);
  stage16(gA1, dA1);
  stage16(gB0, dB0);
  stage16(gB1, dB1);
  __syncthreads();                       // vmcnt(0) drain -> buf0 ready

  int cur = 0;
  for (int k0 = 0; k0 < K; k0 += 32) {
    const int nxt = cur ^ 1;
    if (k0 + 32 < K) {                   // issue next-tile prefetch first
      const int o = nxt * 4096;
      stage16(gA0 + k0 + 32, dA0 + o);
      stage16(gA1 + k0 + 32, dA1 + o);
      stage16(gB0 + k0 + 32, dB0 + o);
      stage16(gB1 + k0 + 32, dB1 + o);
    }
    const int co = cur * 4096;
    bf16x8 afr[4], bfr[4];
#pragma unroll
    for (int t = 0; t < 4; ++t) {
      afr[t] = *(const bf16x8*)(sA + co + fa[t]);
      bfr[t] = *(const bf16x8*)(sB + co + fb[t]);
    }
#pragma unroll
    for (int i = 0; i < 4; ++i)
#pragma unroll
      for (int j = 0; j < 4; ++j)
        acc[i][j] = __builtin_amdgcn_mfma_f32_16x16x32_bf16(afr[i], bfr[j], acc[i][j], 0, 0, 0);
    __syncthreads();                     // reads of cur done + prefetch landed
    cur = nxt;
  }
}

// ============================================================================
// prep: weights -> [N][K] bf16 transposes; pos_emb -> MFMA C-layout order
// ============================================================================
__global__ __launch_bounds__(256) void k_prep(const float* __restrict__ wqkv,
                                              const float* __restrict__ wout,
                                              const float* __restrict__ w1,
                                              const float* __restrict__ w2,
                                              const float* __restrict__ pos,
                                              bf16* __restrict__ wqkvT, bf16* __restrict__ woutT,
                                              bf16* __restrict__ w1T, bf16* __restrict__ w2T,
                                              float* __restrict__ posP)
{
  const int total = 768 * 256 + 256 * 256 + 1024 * 256 + 256 * 1024 + 4096;
  for (int i = blockIdx.x * 256 + threadIdx.x; i < total; i += gridDim.x * 256) {
    int j = i;
    if (j < 768 * 256) { int n = j >> 8, k = j & 255; wqkvT[j] = (bf16)wqkv[k * 768 + n]; continue; }
    j -= 768 * 256;
    if (j < 256 * 256) { int n = j >> 8, k = j & 255; woutT[j] = (bf16)wout[k * 256 + n]; continue; }
    j -= 256 * 256;
    if (j < 1024 * 256) { int n = j >> 8, k = j & 255; w1T[j] = (bf16)w1[k * 1024 + n]; continue; }
    j -= 1024 * 256;
    if (j < 256 * 1024) { int n = j >> 10, k = j & 1023; w2T[j] = (bf16)w2[k * 256 + n]; continue; }
    j -= 256 * 1024;
    { // posP[((mt*4+r)*4+nt)*64 + lane] = pos[i][j] at (i=mt*16+quad*4+r, j=nt*16+c)
      int lane = j & 63, t = j >> 6;
      int nt = t & 3, r = (t >> 2) & 3, mt = t >> 4;
      int ii = mt * 16 + (lane >> 4) * 4 + r, jj = nt * 16 + (lane & 15);
      posP[j] = pos[ii * 64 + jj];
    }
  }
}

// ============================================================================
// layernorm: one wave per token (256 dims = 64 lanes x float4), out bf16
// ============================================================================
__global__ __launch_bounds__(256) void k_ln(const float* __restrict__ x,
                                            const float* __restrict__ gam,
                                            const float* __restrict__ bet,
                                            bf16* __restrict__ out)
{
  const int wave = threadIdx.x >> 6, lane = threadIdx.x & 63;
  const int token = blockIdx.x * 4 + wave;
  const float4 v = ((const float4*)x)[(size_t)token * 64 + lane];
  float s = v.x + v.y + v.z + v.w;
  float q = v.x * v.x + v.y * v.y + v.z * v.z + v.w * v.w;
#pragma unroll
  for (int off = 32; off; off >>= 1) { s += __shfl_xor(s, off); q += __shfl_xor(q, off); }
  const float mu = s * (1.f / 256.f);
  const float var = q * (1.f / 256.f) - mu * mu;
  const float rs = rsqrtf(var + LNEPS);
  const float4 gv = ((const float4*)gam)[lane];
  const float4 bv = ((const float4*)bet)[lane];
  bf16x4 o;
  o[0] = (bf16)((v.x - mu) * rs * gv.x + bv.x);
  o[1] = (bf16)((v.y - mu) * rs * gv.y + bv.y);
  o[2] = (bf16)((v.z - mu) * rs * gv.z + bv.z);
  o[3] = (bf16)((v.w - mu) * rs * gv.w + bv.w);
  *(bf16x4*)(out + (size_t)token * 256 + lane * 4) = o;
}

// ============================================================================
// qkv GEMM: rows read with roll; qkv written in rolled (window) order, bf16
// ============================================================================
__global__ __launch_bounds__(256, 2) void k_gemm_qkv(const bf16* __restrict__ h1,
                                                     const bf16* __restrict__ wqkvT,
                                                     bf16* __restrict__ qkv)
{
  __shared__ __align__(16) bf16 sA[2 * 128 * 32];
  __shared__ __align__(16) bf16 sB[2 * 128 * 32];
  f32x4 acc[4][4];
  int mBase, nBase;
  grid_swz<6>(mBase, nBase);
  gemm_tile<256, 256, true>(h1, wqkvT, mBase, nBase, sA, sB, acc);
  const int lane = threadIdx.x & 63, wave = threadIdx.x >> 6;
  const int c = lane & 15, quad = lane >> 4;
  const int rowBase = mBase + (wave & 1) * 64 + quad * 4;
  const int colBase = nBase + (wave >> 1) * 64 + c;
#pragma unroll
  for (int i = 0; i < 4; ++i)
#pragma unroll
    for (int j = 0; j < 4; ++j)
#pragma unroll
      for (int r = 0; r < 4; ++r)
        qkv[(size_t)(rowBase + i * 16 + r) * QKVN + (colBase + j * 16)] = (bf16)acc[i][j][r];
}

// ============================================================================
// attention: block = 4 waves, one (window, head) per wave; grid (NWIN, 2)
// ============================================================================
__global__ __launch_bounds__(256, 2) void k_attn(const bf16* __restrict__ qkv,
                                                 const float* __restrict__ posP,
                                                 bf16* __restrict__ attn)
{
  __shared__ __align__(16) bf16 sQ[4][64 * 40];  // q [64][32] pad->40 ; reused for P staging
  __shared__ __align__(16) bf16 sK[4][64 * 40];  // k [64][32] pad->40
  __shared__ __align__(16) bf16 sV[4][32 * 72];  // v^T [32][64] pad->72
  const int tid = threadIdx.x;
  const int wave = tid >> 6, lane = tid & 63;
  const int gh = blockIdx.y * 4 + wave;          // global head
  const int win = blockIdx.x;
  const int c = lane & 15, quad = lane >> 4;
  const size_t base = (size_t)win * 64 * QKVN;

  { // q,k: 16B vector loads -> padded LDS
    const int row = lane >> 2;
    const int col = (lane & 3) * 8;
#pragma unroll
    for (int i = 0; i < 4; ++i) {
      int rr = i * 16 + row;
      *(uint4*)(&sQ[wave][rr * 40 + col]) = *(const uint4*)(qkv + base + (size_t)rr * QKVN + gh * 32 + col);
      *(uint4*)(&sK[wave][rr * 40 + col]) = *(const uint4*)(qkv + base + (size_t)rr * QKVN + 256 + gh * 32 + col);
    }
  }
  { // v transposed into [d][j]
    const int d = lane & 31, jh = lane >> 5;
#pragma unroll
    for (int it = 0; it < 32; ++it) {
      int j = it * 2 + jh;
      sV[wave][d * 72 + j] = qkv[base + (size_t)j * QKVN + 512 + gh * 32 + d];
    }
  }

  // ---- S = Q K^T (per-wave private LDS regions; no block barrier needed)
  const f32x4 fzero = {0.f, 0.f, 0.f, 0.f};
  f32x4 sacc[4][4];
#pragma unroll
  for (int i = 0; i < 4; ++i)
#pragma unroll
    for (int j = 0; j < 4; ++j) sacc[i][j] = fzero;
  bf16x8 qf[4], kf[4];
#pragma unroll
  for (int t = 0; t < 4; ++t) {
    qf[t] = *(const bf16x8*)(&sQ[wave][(t * 16 + c) * 40 + quad * 8]);
    kf[t] = *(const bf16x8*)(&sK[wave][(t * 16 + c) * 40 + quad * 8]);
  }
#pragma unroll
  for (int i = 0; i < 4; ++i)
#pragma unroll
    for (int j = 0; j < 4; ++j)
      sacc[i][j] = __builtin_amdgcn_mfma_f32_16x16x32_bf16(qf[i], kf[j], sacc[i][j], 0, 0, 0);

  // ---- scores: scale + pos, row softmax (rows live across 16-lane groups)
  const float scale = 0.17677669529663687f; // 1/sqrt(32)
  float p[4][4][4];
#pragma unroll
  for (int i = 0; i < 4; ++i)
#pragma unroll
    for (int j = 0; j < 4; ++j)
#pragma unroll
      for (int r = 0; r < 4; ++r)
        p[i][j][r] = sacc[i][j][r] * scale + posP[(((i * 4 + r) * 4 + j) << 6) + lane];

  float mx[4][4], rcp[4][4];
#pragma unroll
  for (int i = 0; i < 4; ++i)
#pragma unroll
    for (int r = 0; r < 4; ++r) {
      float m = fmaxf(fmaxf(p[i][0][r], p[i][1][r]), fmaxf(p[i][2][r], p[i][3][r]));
      m = fmaxf(m, __shfl_xor(m, 1)); m = fmaxf(m, __shfl_xor(m, 2));
      m = fmaxf(m, __shfl_xor(m, 4)); m = fmaxf(m, __shfl_xor(m, 8));
      mx[i][r] = m;
    }
#pragma unroll
  for (int i = 0; i < 4; ++i)
#pragma unroll
    for (int r = 0; r < 4; ++r) {
#pragma unroll
      for (int j = 0; j < 4; ++j) p[i][j][r] = __expf(p[i][j][r] - mx[i][r]);
      float t = p[i][0][r] + p[i][1][r] + p[i][2][r] + p[i][3][r];
      t += __shfl_xor(t, 1); t += __shfl_xor(t, 2); t += __shfl_xor(t, 4); t += __shfl_xor(t, 8);
      rcp[i][r] = 1.0f / t;
    }
#pragma unroll
  for (int i = 0; i < 4; ++i)
#pragma unroll
    for (int j = 0; j < 4; ++j)
#pragma unroll
      for (int r = 0; r < 4; ++r) p[i][j][r] *= rcp[i][r];

  // ---- O = P V  (P -> LDS (A-layout) in two j-halves, reusing sQ)
  f32x4 oacc[4][2];
#pragma unroll
  for (int i = 0; i < 4; ++i) { oacc[i][0] = fzero; oacc[i][1] = fzero; }
#pragma unroll
  for (int half = 0; half < 2; ++half) {
#pragma unroll
    for (int i = 0; i < 4; ++i)
#pragma unroll
      for (int j2 = 0; j2 < 2; ++j2)
#pragma unroll
        for (int r = 0; r < 4; ++r)
          sQ[wave][(i * 16 + quad * 4 + r) * 40 + j2 * 16 + c] = (bf16)p[i][half * 2 + j2][r];
    bf16x8 pf[4], vf[2];
#pragma unroll
    for (int t = 0; t < 4; ++t)
      pf[t] = *(const bf16x8*)(&sQ[wave][(t * 16 + c) * 40 + quad * 8]);
#pragma unroll
    for (int n2 = 0; n2 < 2; ++n2)
      vf[n2] = *(const bf16x8*)(&sV[wave][(n2 * 16 + c) * 72 + half * 32 + quad * 8]);
#pragma unroll
    for (int i = 0; i < 4; ++i)
#pragma unroll
      for (int n2 = 0; n2 < 2; ++n2)
        oacc[i][n2] = __builtin_amdgcn_mfma_f32_16x16x32_bf16(pf[i], vf[n2], oacc[i][n2], 0, 0, 0);
  }

#pragma unroll
  for (int i = 0; i < 4; ++i)
#pragma unroll
    for (int n2 = 0; n2 < 2; ++n2)
#pragma unroll
      for (int r = 0; r < 4; ++r)
        attn[(size_t)(win * 64 + i * 16 + quad * 4 + r) * DIM + gh * 32 + n2 * 16 + c] = (bf16)oacc[i][n2][r];
}

// ============================================================================
// out-proj GEMM + b_out + residual(x) with un-roll -> x2 (f32, into d_out)
// ============================================================================
__global__ __launch_bounds__(256, 2) void k_gemm_proj(const bf16* __restrict__ attn,
                                                      const bf16* __restrict__ woutT,
                                                      const float* __restrict__ x,
                                                      const float* __restrict__ b_out,
                                                      float* __restrict__ x2)
{
  __shared__ __align__(16) bf16 sA[2 * 128 * 32];
  __shared__ __align__(16) bf16 sB[2 * 128 * 32];
  f32x4 acc[4][4];
  int mBase, nBase;
  grid_swz<2>(mBase, nBase);
  gemm_tile<256, 256, false>(attn, woutT, mBase, nBase, sA, sB, acc);
  const int lane = threadIdx.x & 63, wave = threadIdx.x >> 6;
  const int c = lane & 15, quad = lane >> 4;
  const int rowBase = mBase + (wave & 1) * 64 + quad * 4;
  const int colBase = nBase + (wave >> 1) * 64 + c;
#pragma unroll
  for (int i = 0; i < 4; ++i)
#pragma unroll
    for (int r = 0; r < 4; ++r) {
      const int rp = rowBase + i * 16 + r;
      const size_t rowoff = (size_t)roll_row(rp) * DIM;
#pragma unroll
      for (int j = 0; j < 4; ++j) {
        const int col = colBase + j * 16;
        x2[rowoff + col] = acc[i][j][r] + b_out[col] + x[rowoff + col];
      }
    }
}

// ============================================================================
// mlp1: h2 @ w1T + b1 -> fast gelu -> g (bf16, ldc = LDC)
// ============================================================================
template<int LDC, int NY>
__global__ __launch_bounds__(256, 2) void k_gemm_mlp1(const bf16* __restrict__ h2,
                                                      const bf16* __restrict__ w1Th,
                                                      const float* __restrict__ b1h,
                                                      bf16* __restrict__ g)
{
  __shared__ __align__(16) bf16 sA[2 * 128 * 32];
  __shared__ __align__(16) bf16 sB[2 * 128 * 32];
  f32x4 acc[4][4];
  int mBase, nBase;
  grid_swz<NY>(mBase, nBase);
  gemm_tile<256, 256, false>(h2, w1Th, mBase, nBase, sA, sB, acc);
  const int lane = threadIdx.x & 63, wave = threadIdx.x >> 6;
  const int c = lane & 15, quad = lane >> 4;
  const int rowBase = mBase + (wave & 1) * 64 + quad * 4;
  const int colBase = nBase + (wave >> 1) * 64 + c;
#pragma unroll
  for (int i = 0; i < 4; ++i)
#pragma unroll
    for (int j = 0; j < 4; ++j) {
      const int col = colBase + j * 16;
      const float bb = b1h[col];
#pragma unroll
      for (int r = 0; r < 4; ++r) {
        const float v = acc[i][j][r] + bb;
        g[(size_t)(rowBase + i * 16 + r) * LDC + col] = (bf16)fast_gelu(v);
      }
    }
}

// ============================================================================
// mlp2: g(K) @ w2T(ldb=1024) [+ b2] accumulated into d_out (x2 resident)
// ============================================================================
template<int K>
__global__ __launch_bounds__(256, 2) void k_gemm_mlp2(const bf16* __restrict__ g,
                                                      const bf16* __restrict__ w2Th,
                                                      const float* __restrict__ b2,
                                                      float* __restrict__ out,
                                                      int first)
{
  __shared__ __align__(16) bf16 sA[2 * 128 * 32];
  __shared__ __align__(16) bf16 sB[2 * 128 * 32];
  f32x4 acc[4][4];
  int mBase, nBase;
  grid_swz<2>(mBase, nBase);
  gemm_tile<K, 1024, false>(g, w2Th, mBase, nBase, sA, sB, acc);
  const int lane = threadIdx.x & 63, wave = threadIdx.x >> 6;
  const int c = lane & 15, quad = lane >> 4;
  const int rowBase = mBase + (wave & 1) * 64 + quad * 4;
  const int colBase = nBase + (wave >> 1) * 64 + c;
#pragma unroll
  for (int i = 0; i < 4; ++i)
#pragma unroll
    for (int j = 0; j < 4; ++j) {
      const int col = colBase + j * 16;
      const float bb = first ? b2[col] : 0.0f;
#pragma unroll
      for (int r = 0; r < 4; ++r) {
        const size_t off = (size_t)(rowBase + i * 16 + r) * DIM + col;
        out[off] = out[off] + acc[i][j][r] + bb;
      }
    }
}

// ============================================================================
extern "C" void kernel_launch(void* const* d_in, const int* in_sizes, int n_in,
                              void* d_out, int out_size, void* d_ws, size_t ws_size,
                              hipStream_t stream) {
  const float* x    = (const float*)d_in[0];
  const float* wqkv = (const float*)d_in[1];
  const float* wout = (const float*)d_in[2];
  const float* bo   = (const float*)d_in[3];
  const float* pos  = (const float*)d_in[4];
  const float* l1g  = (const float*)d_in[5];
  const float* l1b  = (const float*)d_in[6];
  const float* w1   = (const float*)d_in[7];
  const float* b1   = (const float*)d_in[8];
  const float* w2   = (const float*)d_in[9];
  const float* b2   = (const float*)d_in[10];
  const float* l2g  = (const float*)d_in[11];
  const float* l2b  = (const float*)d_in[12];
  float* out = (float*)d_out;

  char* ws = (char*)d_ws;
  const size_t WEIGHTS_SZ = (size_t)768 * 256 * 2 + 256 * 256 * 2 + 1024 * 256 * 2
                          + 256 * 1024 * 2 + 4096 * 4;
  // fused-MLP layout needs: g full [131072][1024] bf16 at ws+67MB (ends 335.5MB) + weights
  const size_t FUSED_NEED = 67108864ull + 268435456ull + WEIGHTS_SZ;
  const bool fused = ws_size >= FUSED_NEED;

  bf16* h1   = (bf16*)ws;                              // [0, 67MB)
  bf16* qkv  = (bf16*)(ws + 67108864);                 // [67, 268MB)
  bf16* attn = h1;                                     // reuse (h1 dead after qkv GEMM)
  bf16* h2;
  bf16* gbuf;
  char* wp;
  if (fused) {
    h2   = (bf16*)ws;                                  // [0,67MB): attn dead after proj
    gbuf = (bf16*)(ws + 67108864);                     // [67, 335.5MB): qkv dead after attn
    wp   = ws + 67108864 + 268435456;
  } else {
    h2   = qkv;                                        // [67, 134MB)
    gbuf = (bf16*)(ws + 134217728);                    // [134, 268MB)
    wp   = ws + 268435456;
  }
  bf16* wqkvT = (bf16*)wp;  wp += 768 * 256 * 2;
  bf16* woutT = (bf16*)wp;  wp += 256 * 256 * 2;
  bf16* w1T   = (bf16*)wp;  wp += 1024 * 256 * 2;
  bf16* w2T   = (bf16*)wp;  wp += 256 * 1024 * 2;
  float* posP = (float*)wp;                            // 4096 f32

  k_prep<<<dim3(1024), dim3(256), 0, stream>>>(wqkv, wout, w1, w2, pos, wqkvT, woutT, w1T, w2T, posP);
  k_ln<<<dim3(NTOK / 4), dim3(256), 0, stream>>>(x, l1g, l1b, h1);
  k_gemm_qkv<<<dim3(6144), dim3(256), 0, stream>>>(h1, wqkvT, qkv);
  k_attn<<<dim3(NWIN, 2), dim3(256), 0, stream>>>(qkv, posP, attn);
  k_gemm_proj<<<dim3(2048), dim3(256), 0, stream>>>(attn, woutT, x, bo, out);
  k_ln<<<dim3(NTOK / 4), dim3(256), 0, stream>>>(out, l2g, l2b, h2);
  if (fused) {
    k_gemm_mlp1<1024, 8><<<dim3(8192), dim3(256), 0, stream>>>(h2, w1T, b1, gbuf);
    k_gemm_mlp2<1024><<<dim3(2048), dim3(256), 0, stream>>>(gbuf, w2T, b2, out, 1);
  } else {
    for (int half = 0; half < 2; ++half) {
      k_gemm_mlp1<512, 4><<<dim3(4096), dim3(256), 0, stream>>>(h2, w1T + half * 512 * 256, b1 + half * 512, gbuf);
      k_gemm_mlp2<512><<<dim3(2048), dim3(256), 0, stream>>>(gbuf, w2T + half * 512, b2, out, half == 0 ? 1 : 0);
    }
  }
}

// Round 3
// 797.082 us; speedup vs baseline: 1.1879x; 1.0005x over previous
//
#include <hip/hip_runtime.h>
#include <hip/hip_bf16.h>
#include <math.h>
#include <stdint.h>

#define DIM   256
#define NSEQ  65536
#define NTOK  131072
#define HEADS 8
#define HD    32
#define WSZ   64
#define NWIN  2048
#define QKVN  768
#define MLPD  1024
#define LNEPS 1e-5f

typedef __bf16 bf16;
typedef __bf16 bf16x8 __attribute__((ext_vector_type(8)));
typedef __bf16 bf16x4 __attribute__((ext_vector_type(4)));
typedef float  f32x4  __attribute__((ext_vector_type(4)));

// rolled-window row rp -> source/original token index (shift = 32, per batch of 65536)
__device__ __forceinline__ int roll_row(int r) {
  return (r & 0x10000) | ((r + 32) & 0xFFFF);
}

// fast GELU: tanh-approx rewritten as v * sigmoid(1.5957691*v + 0.0713548*v^3).
__device__ __forceinline__ float fast_gelu(float v) {
  const float x2 = v * v;
  const float z2 = v * __builtin_fmaf(x2, 0.07135481630268f, 1.5957691216057308f);
  const float e  = __expf(z2);
  const float r  = __builtin_amdgcn_rcpf(e + 1.0f);
  return __builtin_fmaf(-v, r, v);   // v * (1 - r) = v * sigmoid(z2)
}

// XCD-chunked bijective block swizzle, N-block fastest within each XCD chunk.
template<int NY>
__device__ __forceinline__ void grid_swz(int& mBase, int& nBase) {
  const int nwg  = gridDim.x;
  const int lin  = blockIdx.x;
  const int orig = (lin & 7) * (nwg >> 3) + (lin >> 3);
  mBase = (orig / NY) * 128;
  nBase = (orig % NY) * 128;
}

// ---- async global->LDS 16B stage. LDS dest is wave-uniform base + lane*16.
__device__ __forceinline__ void stage16(const bf16* g, bf16* l) {
#if __has_builtin(__builtin_amdgcn_global_load_lds)
  __builtin_amdgcn_global_load_lds((const __attribute__((address_space(1))) void*)g,
                                   (__attribute__((address_space(3))) void*)l, 16, 0, 0);
#else
  int lane = threadIdx.x & 63;
  *(uint4*)((char*)l + lane * 16) = *(const uint4*)g;
#endif
}

#define TILE_ELEMS 4096   // 128 rows x 32 k, bf16

// one compute phase: ds_read frags from buffer `co`, read-done barrier, 16 MFMA
__device__ __forceinline__ void gemm_step(const bf16* sA, const bf16* sB, int co,
                                          const int fa[4], const int fb[4],
                                          f32x4 acc[4][4])
{
  bf16x8 afr[4], bfr[4];
#pragma unroll
  for (int t = 0; t < 4; ++t) {
    afr[t] = *(const bf16x8*)(sA + co + fa[t]);
    bfr[t] = *(const bf16x8*)(sB + co + fb[t]);
  }
  // my LDS reads complete -> barrier: ALL waves' reads complete -> safe to re-stage buffer
  asm volatile("s_waitcnt lgkmcnt(0)" ::: "memory");
  __builtin_amdgcn_s_barrier();
  __builtin_amdgcn_sched_barrier(0);
#pragma unroll
  for (int i = 0; i < 4; ++i)
#pragma unroll
    for (int j = 0; j < 4; ++j)
      acc[i][j] = __builtin_amdgcn_mfma_f32_16x16x32_bf16(afr[i], bfr[j], acc[i][j], 0, 0, 0);
}

// ============================================================================
// GEMM core: C[128x128] = A[128xK] * Bt[128xK]^T  (A row-major, Bt = B^T row-major)
// 256 threads = 4 waves in 2x2, wave tile 64x64 via 16 x mfma_f32_16x16x32_bf16.
// Triple-buffered LDS [3][128][32] bf16, XOR-swizzled 16B chunks.
// Depth-2 pipeline with COUNTED vmcnt (never drains to 0 in main loop):
//   iter t: issue chunk t+2 -> vmcnt(8) [chunk t landed] -> barrier -> ds_read
//           -> lgkmcnt(0)+barrier [WAR guard] -> MFMA.
// Each wave issues exactly 4 global_load_lds per chunk; vmcnt completes in issue
// order (m135), so vmcnt(8) == "2 newest chunks may still fly, chunk t is home".
// ============================================================================
template<int K, int LDB, bool ROLL>
__device__ __forceinline__ void gemm_tile(const bf16* __restrict__ A,
                                          const bf16* __restrict__ Bt,
                                          int mBase, int nBase,
                                          bf16* sA, bf16* sB,   // each [3*TILE_ELEMS]
                                          f32x4 acc[4][4])
{
  const int tid  = threadIdx.x;
  const int wave = tid >> 6;
  const int lane = tid & 63;
  const int slot = lane & 3;
  const int swz  = (lane >> 3) & 3;          // ((tile_row>>1)&3) for this lane's staging row
  const int rloc = lane >> 2;                // 0..15
  const int chunk = ((slot ^ swz) * 8);      // swizzled k-chunk (elements)

  int lr0 = mBase + wave * 32 + rloc;
  int lr1 = lr0 + 16;
  int ar0 = ROLL ? roll_row(lr0) : lr0;
  int ar1 = ROLL ? roll_row(lr1) : lr1;
  const bf16* gA0 = A + (size_t)ar0 * K + chunk;
  const bf16* gA1 = A + (size_t)ar1 * K + chunk;
  const bf16* gB0 = Bt + (size_t)(nBase + wave * 32 + rloc) * LDB + chunk;
  const bf16* gB1 = Bt + (size_t)(nBase + wave * 32 + rloc + 16) * LDB + chunk;

  bf16* dA0 = sA + (wave * 32 +  0) * 32;
  bf16* dA1 = sA + (wave * 32 + 16) * 32;
  bf16* dB0 = sB + (wave * 32 +  0) * 32;
  bf16* dB1 = sB + (wave * 32 + 16) * 32;

  const int m0 = (wave & 1) * 64;
  const int n0 = (wave >> 1) * 64;
  const int c    = lane & 15;
  const int quad = lane >> 4;

  int fa[4], fb[4];
#pragma unroll
  for (int t = 0; t < 4; ++t) {
    int rowA = m0 + t * 16 + c;
    fa[t] = rowA * 32 + ((quad ^ ((rowA >> 1) & 3)) * 8);
    int rowB = n0 + t * 16 + c;
    fb[t] = rowB * 32 + ((quad ^ ((rowB >> 1) & 3)) * 8);
  }

  const f32x4 fzero = {0.f, 0.f, 0.f, 0.f};
#pragma unroll
  for (int i = 0; i < 4; ++i)
#pragma unroll
    for (int j = 0; j < 4; ++j) acc[i][j] = fzero;

  constexpr int NT = K / 32;
  static_assert(NT >= 3, "need at least 3 k-chunks");

  // prologue: stage chunks 0 and 1 into buffers 0 and 1 (8 loads/wave in flight)
  stage16(gA0, dA0);
  stage16(gA1, dA1);
  stage16(gB0, dB0);
  stage16(gB1, dB1);
  stage16(gA0 + 32, dA0 + TILE_ELEMS);
  stage16(gA1 + 32, dA1 + TILE_ELEMS);
  stage16(gB0 + 32, dB0 + TILE_ELEMS);
  stage16(gB1 + 32, dB1 + TILE_ELEMS);

  int cur = 0;
  for (int t = 0; t < NT - 2; ++t) {
    const int nxt2 = (cur == 0) ? 2 : cur - 1;      // (cur+2)%3
    const int o = nxt2 * TILE_ELEMS;
    const int k2 = (t + 2) * 32;
    stage16(gA0 + k2, dA0 + o);
    stage16(gA1 + k2, dA1 + o);
    stage16(gB0 + k2, dB0 + o);
    stage16(gB1 + k2, dB1 + o);
    // chunk t landed; chunks t+1, t+2 (8 loads) may still be in flight
    asm volatile("s_waitcnt vmcnt(8)" ::: "memory");
    __builtin_amdgcn_s_barrier();
    __builtin_amdgcn_sched_barrier(0);
    gemm_step(sA, sB, cur * TILE_ELEMS, fa, fb, acc);
    cur = (cur == 2) ? 0 : cur + 1;
  }
  // t = NT-2: chunk landed, one chunk (4 loads) still in flight
  asm volatile("s_waitcnt vmcnt(4)" ::: "memory");
  __builtin_amdgcn_s_barrier();
  __builtin_amdgcn_sched_barrier(0);
  gemm_step(sA, sB, cur * TILE_ELEMS, fa, fb, acc);
  cur = (cur == 2) ? 0 : cur + 1;
  // t = NT-1: drain
  asm volatile("s_waitcnt vmcnt(0)" ::: "memory");
  __builtin_amdgcn_s_barrier();
  __builtin_amdgcn_sched_barrier(0);
  gemm_step(sA, sB, cur * TILE_ELEMS, fa, fb, acc);
}

// ============================================================================
// prep: weights -> [N][K] bf16 transposes; pos_emb -> MFMA C-layout order
// ============================================================================
__global__ __launch_bounds__(256) void k_prep(const float* __restrict__ wqkv,
                                              const float* __restrict__ wout,
                                              const float* __restrict__ w1,
                                              const float* __restrict__ w2,
                                              const float* __restrict__ pos,
                                              bf16* __restrict__ wqkvT, bf16* __restrict__ woutT,
                                              bf16* __restrict__ w1T, bf16* __restrict__ w2T,
                                              float* __restrict__ posP)
{
  const int total = 768 * 256 + 256 * 256 + 1024 * 256 + 256 * 1024 + 4096;
  for (int i = blockIdx.x * 256 + threadIdx.x; i < total; i += gridDim.x * 256) {
    int j = i;
    if (j < 768 * 256) { int n = j >> 8, k = j & 255; wqkvT[j] = (bf16)wqkv[k * 768 + n]; continue; }
    j -= 768 * 256;
    if (j < 256 * 256) { int n = j >> 8, k = j & 255; woutT[j] = (bf16)wout[k * 256 + n]; continue; }
    j -= 256 * 256;
    if (j < 1024 * 256) { int n = j >> 8, k = j & 255; w1T[j] = (bf16)w1[k * 1024 + n]; continue; }
    j -= 1024 * 256;
    if (j < 256 * 1024) { int n = j >> 10, k = j & 1023; w2T[j] = (bf16)w2[k * 256 + n]; continue; }
    j -= 256 * 1024;
    { // posP[((mt*4+r)*4+nt)*64 + lane] = pos[i][j] at (i=mt*16+quad*4+r, j=nt*16+c)
      int lane = j & 63, t = j >> 6;
      int nt = t & 3, r = (t >> 2) & 3, mt = t >> 4;
      int ii = mt * 16 + (lane >> 4) * 4 + r, jj = nt * 16 + (lane & 15);
      posP[j] = pos[ii * 64 + jj];
    }
  }
}

// ============================================================================
// layernorm: one wave per token (256 dims = 64 lanes x float4), out bf16
// ============================================================================
__global__ __launch_bounds__(256) void k_ln(const float* __restrict__ x,
                                            const float* __restrict__ gam,
                                            const float* __restrict__ bet,
                                            bf16* __restrict__ out)
{
  const int wave = threadIdx.x >> 6, lane = threadIdx.x & 63;
  const int token = blockIdx.x * 4 + wave;
  const float4 v = ((const float4*)x)[(size_t)token * 64 + lane];
  float s = v.x + v.y + v.z + v.w;
  float q = v.x * v.x + v.y * v.y + v.z * v.z + v.w * v.w;
#pragma unroll
  for (int off = 32; off; off >>= 1) { s += __shfl_xor(s, off); q += __shfl_xor(q, off); }
  const float mu = s * (1.f / 256.f);
  const float var = q * (1.f / 256.f) - mu * mu;
  const float rs = rsqrtf(var + LNEPS);
  const float4 gv = ((const float4*)gam)[lane];
  const float4 bv = ((const float4*)bet)[lane];
  bf16x4 o;
  o[0] = (bf16)((v.x - mu) * rs * gv.x + bv.x);
  o[1] = (bf16)((v.y - mu) * rs * gv.y + bv.y);
  o[2] = (bf16)((v.z - mu) * rs * gv.z + bv.z);
  o[3] = (bf16)((v.w - mu) * rs * gv.w + bv.w);
  *(bf16x4*)(out + (size_t)token * 256 + lane * 4) = o;
}

// ============================================================================
// qkv GEMM: rows read with roll; qkv written in rolled (window) order, bf16
// ============================================================================
__global__ __launch_bounds__(256, 2) void k_gemm_qkv(const bf16* __restrict__ h1,
                                                     const bf16* __restrict__ wqkvT,
                                                     bf16* __restrict__ qkv)
{
  __shared__ __align__(16) bf16 sA[3 * TILE_ELEMS];
  __shared__ __align__(16) bf16 sB[3 * TILE_ELEMS];
  f32x4 acc[4][4];
  int mBase, nBase;
  grid_swz<6>(mBase, nBase);
  gemm_tile<256, 256, true>(h1, wqkvT, mBase, nBase, sA, sB, acc);
  const int lane = threadIdx.x & 63, wave = threadIdx.x >> 6;
  const int c = lane & 15, quad = lane >> 4;
  const int rowBase = mBase + (wave & 1) * 64 + quad * 4;
  const int colBase = nBase + (wave >> 1) * 64 + c;
#pragma unroll
  for (int i = 0; i < 4; ++i)
#pragma unroll
    for (int j = 0; j < 4; ++j)
#pragma unroll
      for (int r = 0; r < 4; ++r)
        qkv[(size_t)(rowBase + i * 16 + r) * QKVN + (colBase + j * 16)] = (bf16)acc[i][j][r];
}

// ============================================================================
// attention: block = 4 waves, one (window, head) per wave; grid (NWIN, 2)
// ============================================================================
__global__ __launch_bounds__(256, 2) void k_attn(const bf16* __restrict__ qkv,
                                                 const float* __restrict__ posP,
                                                 bf16* __restrict__ attn)
{
  __shared__ __align__(16) bf16 sQ[4][64 * 40];  // q [64][32] pad->40 ; reused for P staging
  __shared__ __align__(16) bf16 sK[4][64 * 40];  // k [64][32] pad->40
  __shared__ __align__(16) bf16 sV[4][32 * 72];  // v^T [32][64] pad->72
  const int tid = threadIdx.x;
  const int wave = tid >> 6, lane = tid & 63;
  const int gh = blockIdx.y * 4 + wave;          // global head
  const int win = blockIdx.x;
  const int c = lane & 15, quad = lane >> 4;
  const size_t base = (size_t)win * 64 * QKVN;

  { // q,k: 16B vector loads -> padded LDS
    const int row = lane >> 2;
    const int col = (lane & 3) * 8;
#pragma unroll
    for (int i = 0; i < 4; ++i) {
      int rr = i * 16 + row;
      *(uint4*)(&sQ[wave][rr * 40 + col]) = *(const uint4*)(qkv + base + (size_t)rr * QKVN + gh * 32 + col);
      *(uint4*)(&sK[wave][rr * 40 + col]) = *(const uint4*)(qkv + base + (size_t)rr * QKVN + 256 + gh * 32 + col);
    }
  }
  { // v transposed into [d][j]
    const int d = lane & 31, jh = lane >> 5;
#pragma unroll
    for (int it = 0; it < 32; ++it) {
      int j = it * 2 + jh;
      sV[wave][d * 72 + j] = qkv[base + (size_t)j * QKVN + 512 + gh * 32 + d];
    }
  }

  // ---- S = Q K^T (per-wave private LDS regions; no block barrier needed)
  const f32x4 fzero = {0.f, 0.f, 0.f, 0.f};
  f32x4 sacc[4][4];
#pragma unroll
  for (int i = 0; i < 4; ++i)
#pragma unroll
    for (int j = 0; j < 4; ++j) sacc[i][j] = fzero;
  bf16x8 qf[4], kf[4];
#pragma unroll
  for (int t = 0; t < 4; ++t) {
    qf[t] = *(const bf16x8*)(&sQ[wave][(t * 16 + c) * 40 + quad * 8]);
    kf[t] = *(const bf16x8*)(&sK[wave][(t * 16 + c) * 40 + quad * 8]);
  }
#pragma unroll
  for (int i = 0; i < 4; ++i)
#pragma unroll
    for (int j = 0; j < 4; ++j)
      sacc[i][j] = __builtin_amdgcn_mfma_f32_16x16x32_bf16(qf[i], kf[j], sacc[i][j], 0, 0, 0);

  // ---- scores: scale + pos, row softmax (rows live across 16-lane groups)
  const float scale = 0.17677669529663687f; // 1/sqrt(32)
  float p[4][4][4];
#pragma unroll
  for (int i = 0; i < 4; ++i)
#pragma unroll
    for (int j = 0; j < 4; ++j)
#pragma unroll
      for (int r = 0; r < 4; ++r)
        p[i][j][r] = sacc[i][j][r] * scale + posP[(((i * 4 + r) * 4 + j) << 6) + lane];

  float mx[4][4], rcp[4][4];
#pragma unroll
  for (int i = 0; i < 4; ++i)
#pragma unroll
    for (int r = 0; r < 4; ++r) {
      float m = fmaxf(fmaxf(p[i][0][r], p[i][1][r]), fmaxf(p[i][2][r], p[i][3][r]));
      m = fmaxf(m, __shfl_xor(m, 1)); m = fmaxf(m, __shfl_xor(m, 2));
      m = fmaxf(m, __shfl_xor(m, 4)); m = fmaxf(m, __shfl_xor(m, 8));
      mx[i][r] = m;
    }
#pragma unroll
  for (int i = 0; i < 4; ++i)
#pragma unroll
    for (int r = 0; r < 4; ++r) {
#pragma unroll
      for (int j = 0; j < 4; ++j) p[i][j][r] = __expf(p[i][j][r] - mx[i][r]);
      float t = p[i][0][r] + p[i][1][r] + p[i][2][r] + p[i][3][r];
      t += __shfl_xor(t, 1); t += __shfl_xor(t, 2); t += __shfl_xor(t, 4); t += __shfl_xor(t, 8);
      rcp[i][r] = 1.0f / t;
    }
#pragma unroll
  for (int i = 0; i < 4; ++i)
#pragma unroll
    for (int j = 0; j < 4; ++j)
#pragma unroll
      for (int r = 0; r < 4; ++r) p[i][j][r] *= rcp[i][r];

  // ---- O = P V  (P -> LDS (A-layout) in two j-halves, reusing sQ)
  f32x4 oacc[4][2];
#pragma unroll
  for (int i = 0; i < 4; ++i) { oacc[i][0] = fzero; oacc[i][1] = fzero; }
#pragma unroll
  for (int half = 0; half < 2; ++half) {
#pragma unroll
    for (int i = 0; i < 4; ++i)
#pragma unroll
      for (int j2 = 0; j2 < 2; ++j2)
#pragma unroll
        for (int r = 0; r < 4; ++r)
          sQ[wave][(i * 16 + quad * 4 + r) * 40 + j2 * 16 + c] = (bf16)p[i][half * 2 + j2][r];
    bf16x8 pf[4], vf[2];
#pragma unroll
    for (int t = 0; t < 4; ++t)
      pf[t] = *(const bf16x8*)(&sQ[wave][(t * 16 + c) * 40 + quad * 8]);
#pragma unroll
    for (int n2 = 0; n2 < 2; ++n2)
      vf[n2] = *(const bf16x8*)(&sV[wave][(n2 * 16 + c) * 72 + half * 32 + quad * 8]);
#pragma unroll
    for (int i = 0; i < 4; ++i)
#pragma unroll
      for (int n2 = 0; n2 < 2; ++n2)
        oacc[i][n2] = __builtin_amdgcn_mfma_f32_16x16x32_bf16(pf[i], vf[n2], oacc[i][n2], 0, 0, 0);
  }

#pragma unroll
  for (int i = 0; i < 4; ++i)
#pragma unroll
    for (int n2 = 0; n2 < 2; ++n2)
#pragma unroll
      for (int r = 0; r < 4; ++r)
        attn[(size_t)(win * 64 + i * 16 + quad * 4 + r) * DIM + gh * 32 + n2 * 16 + c] = (bf16)oacc[i][n2][r];
}

// ============================================================================
// out-proj GEMM + b_out + residual(x) with un-roll -> x2 (f32, into d_out)
// ============================================================================
__global__ __launch_bounds__(256, 2) void k_gemm_proj(const bf16* __restrict__ attn,
                                                      const bf16* __restrict__ woutT,
                                                      const float* __restrict__ x,
                                                      const float* __restrict__ b_out,
                                                      float* __restrict__ x2)
{
  __shared__ __align__(16) bf16 sA[3 * TILE_ELEMS];
  __shared__ __align__(16) bf16 sB[3 * TILE_ELEMS];
  f32x4 acc[4][4];
  int mBase, nBase;
  grid_swz<2>(mBase, nBase);
  gemm_tile<256, 256, false>(attn, woutT, mBase, nBase, sA, sB, acc);
  const int lane = threadIdx.x & 63, wave = threadIdx.x >> 6;
  const int c = lane & 15, quad = lane >> 4;
  const int rowBase = mBase + (wave & 1) * 64 + quad * 4;
  const int colBase = nBase + (wave >> 1) * 64 + c;
#pragma unroll
  for (int i = 0; i < 4; ++i)
#pragma unroll
    for (int r = 0; r < 4; ++r) {
      const int rp = rowBase + i * 16 + r;
      const size_t rowoff = (size_t)roll_row(rp) * DIM;
#pragma unroll
      for (int j = 0; j < 4; ++j) {
        const int col = colBase + j * 16;
        x2[rowoff + col] = acc[i][j][r] + b_out[col] + x[rowoff + col];
      }
    }
}

// ============================================================================
// mlp1: h2 @ w1T + b1 -> fast gelu -> g (bf16, ldc = LDC)
// ============================================================================
template<int LDC, int NY>
__global__ __launch_bounds__(256, 2) void k_gemm_mlp1(const bf16* __restrict__ h2,
                                                      const bf16* __restrict__ w1Th,
                                                      const float* __restrict__ b1h,
                                                      bf16* __restrict__ g)
{
  __shared__ __align__(16) bf16 sA[3 * TILE_ELEMS];
  __shared__ __align__(16) bf16 sB[3 * TILE_ELEMS];
  f32x4 acc[4][4];
  int mBase, nBase;
  grid_swz<NY>(mBase, nBase);
  gemm_tile<256, 256, false>(h2, w1Th, mBase, nBase, sA, sB, acc);
  const int lane = threadIdx.x & 63, wave = threadIdx.x >> 6;
  const int c = lane & 15, quad = lane >> 4;
  const int rowBase = mBase + (wave & 1) * 64 + quad * 4;
  const int colBase = nBase + (wave >> 1) * 64 + c;
#pragma unroll
  for (int i = 0; i < 4; ++i)
#pragma unroll
    for (int j = 0; j < 4; ++j) {
      const int col = colBase + j * 16;
      const float bb = b1h[col];
#pragma unroll
      for (int r = 0; r < 4; ++r) {
        const float v = acc[i][j][r] + bb;
        g[(size_t)(rowBase + i * 16 + r) * LDC + col] = (bf16)fast_gelu(v);
      }
    }
}

// ============================================================================
// mlp2: g(K) @ w2T(ldb=1024) [+ b2] accumulated into d_out (x2 resident)
// ============================================================================
template<int K>
__global__ __launch_bounds__(256, 2) void k_gemm_mlp2(const bf16* __restrict__ g,
                                                      const bf16* __restrict__ w2Th,
                                                      const float* __restrict__ b2,
                                                      float* __restrict__ out,
                                                      int first)
{
  __shared__ __align__(16) bf16 sA[3 * TILE_ELEMS];
  __shared__ __align__(16) bf16 sB[3 * TILE_ELEMS];
  f32x4 acc[4][4];
  int mBase, nBase;
  grid_swz<2>(mBase, nBase);
  gemm_tile<K, 1024, false>(g, w2Th, mBase, nBase, sA, sB, acc);
  const int lane = threadIdx.x & 63, wave = threadIdx.x >> 6;
  const int c = lane & 15, quad = lane >> 4;
  const int rowBase = mBase + (wave & 1) * 64 + quad * 4;
  const int colBase = nBase + (wave >> 1) * 64 + c;
#pragma unroll
  for (int i = 0; i < 4; ++i)
#pragma unroll
    for (int j = 0; j < 4; ++j) {
      const int col = colBase + j * 16;
      const float bb = first ? b2[col] : 0.0f;
#pragma unroll
      for (int r = 0; r < 4; ++r) {
        const size_t off = (size_t)(rowBase + i * 16 + r) * DIM + col;
        out[off] = out[off] + acc[i][j][r] + bb;
      }
    }
}

// ============================================================================
extern "C" void kernel_launch(void* const* d_in, const int* in_sizes, int n_in,
                              void* d_out, int out_size, void* d_ws, size_t ws_size,
                              hipStream_t stream) {
  const float* x    = (const float*)d_in[0];
  const float* wqkv = (const float*)d_in[1];
  const float* wout = (const float*)d_in[2];
  const float* bo   = (const float*)d_in[3];
  const float* pos  = (const float*)d_in[4];
  const float* l1g  = (const float*)d_in[5];
  const float* l1b  = (const float*)d_in[6];
  const float* w1   = (const float*)d_in[7];
  const float* b1   = (const float*)d_in[8];
  const float* w2   = (const float*)d_in[9];
  const float* b2   = (const float*)d_in[10];
  const float* l2g  = (const float*)d_in[11];
  const float* l2b  = (const float*)d_in[12];
  float* out = (float*)d_out;

  char* ws = (char*)d_ws;
  const size_t WEIGHTS_SZ = (size_t)768 * 256 * 2 + 256 * 256 * 2 + 1024 * 256 * 2
                          + 256 * 1024 * 2 + 4096 * 4;
  // fused-MLP layout needs: g full [131072][1024] bf16 at ws+67MB (ends 335.5MB) + weights
  const size_t FUSED_NEED = 67108864ull + 268435456ull + WEIGHTS_SZ;
  const bool fused = ws_size >= FUSED_NEED;

  bf16* h1   = (bf16*)ws;                              // [0, 67MB)
  bf16* qkv  = (bf16*)(ws + 67108864);                 // [67, 268MB)
  bf16* attn = h1;                                     // reuse (h1 dead after qkv GEMM)
  bf16* h2;
  bf16* gbuf;
  char* wp;
  if (fused) {
    h2   = (bf16*)ws;                                  // [0,67MB): attn dead after proj
    gbuf = (bf16*)(ws + 67108864);                     // [67, 335.5MB): qkv dead after attn
    wp   = ws + 67108864 + 268435456;
  } else {
    h2   = qkv;                                        // [67, 134MB)
    gbuf = (bf16*)(ws + 134217728);                    // [134, 268MB)
    wp   = ws + 268435456;
  }
  bf16* wqkvT = (bf16*)wp;  wp += 768 * 256 * 2;
  bf16* woutT = (bf16*)wp;  wp += 256 * 256 * 2;
  bf16* w1T   = (bf16*)wp;  wp += 1024 * 256 * 2;
  bf16* w2T   = (bf16*)wp;  wp += 256 * 1024 * 2;
  float* posP = (float*)wp;                            // 4096 f32

  k_prep<<<dim3(1024), dim3(256), 0, stream>>>(wqkv, wout, w1, w2, pos, wqkvT, woutT, w1T, w2T, posP);
  k_ln<<<dim3(NTOK / 4), dim3(256), 0, stream>>>(x, l1g, l1b, h1);
  k_gemm_qkv<<<dim3(6144), dim3(256), 0, stream>>>(h1, wqkvT, qkv);
  k_attn<<<dim3(NWIN, 2), dim3(256), 0, stream>>>(qkv, posP, attn);
  k_gemm_proj<<<dim3(2048), dim3(256), 0, stream>>>(attn, woutT, x, bo, out);
  k_ln<<<dim3(NTOK / 4), dim3(256), 0, stream>>>(out, l2g, l2b, h2);
  if (fused) {
    k_gemm_mlp1<1024, 8><<<dim3(8192), dim3(256), 0, stream>>>(h2, w1T, b1, gbuf);
    k_gemm_mlp2<1024><<<dim3(2048), dim3(256), 0, stream>>>(gbuf, w2T, b2, out, 1);
  } else {
    for (int half = 0; half < 2; ++half) {
      k_gemm_mlp1<512, 4><<<dim3(4096), dim3(256), 0, stream>>>(h2, w1T + half * 512 * 256, b1 + half * 512, gbuf);
      k_gemm_mlp2<512><<<dim3(2048), dim3(256), 0, stream>>>(gbuf, w2T + half * 512, b2, out, half == 0 ? 1 : 0);
    }
  }
}